// Round 7
// baseline (721.205 us; speedup 1.0000x reference)
//
#include <hip/hip_runtime.h>
#include <math.h>

constexpr int Hc = 80, Wc = 80, Bn = 4, C1 = 256, C2 = 256;
constexpr int HWn = Hc * Wc;          // 6400
constexpr int NPIX = Bn * HWn;        // 25600
constexpr int OFFC = 27;

typedef short bf16x8 __attribute__((ext_vector_type(8)));
typedef float f32x4  __attribute__((ext_vector_type(4)));

__device__ __forceinline__ unsigned f2bf(float f) {   // RNE to bf16 bits
    unsigned u = __float_as_uint(f);
    return (u + 0x7FFF + ((u >> 16) & 1)) >> 16;
}
__device__ __forceinline__ float bf2f(unsigned b) { return __uint_as_float(b << 16); }

// ---------------- kernel 0: weight prep -> per-step LDS images ----------------
// wB[s][split][oc][40] bf16, s = p*8+cc (72 steps), kc<32 real, kc>=32 pad=0
__global__ __launch_bounds__(256) void k_wprep(const float* __restrict__ weight,
                                               unsigned short* __restrict__ wB)
{
    int e = blockIdx.x * 256 + threadIdx.x;   // 0 .. 1474559
    int kc = e % 40;
    int oc = (e / 40) & 255;
    int sp = (e / 10240) & 1;
    int s  = e / 20480;
    int p  = s >> 3, cc = s & 7;
    float w = 0.f;
    if (kc < 32) w = weight[((size_t)oc * C1 + cc * 32 + kc) * 9 + p];
    unsigned hb = f2bf(w);
    unsigned val = sp ? f2bf(w - bf2f(hb)) : hb;
    wB[e] = (unsigned short)val;
}

// ---------------- kernel 1a: init off buffer with b_off ----------------
__global__ __launch_bounds__(256) void k_offinit(const float* __restrict__ b_off,
                                                 float* __restrict__ off)
{
    int t = blockIdx.x * 256 + threadIdx.x;   // 0 .. 691199
    int ch = (t / HWn) % OFFC;
    off[t] = b_off[ch];
}

// ---------------- kernel 1b: offset conv (LDS-tiled, c-split 8) ----------------
__global__ __launch_bounds__(256) void k_offconv2(const float* __restrict__ x,
                                                  const float* __restrict__ w_off,
                                                  float* __restrict__ off)
{
    __shared__ float xs[8][18][18];

    int tid  = threadIdx.x;
    int bidx = blockIdx.x;                 // 0..799
    int wt = bidx % 5;
    int ht = (bidx / 5) % 5;
    int b  = (bidx / 25) % 4;
    int cg = bidx / 100;                   // 0..7
    int h0 = ht * 16, w0 = wt * 16;
    int c0 = cg * 32;
    int ph = tid >> 4, pw = tid & 15;

    float acc[27];
    #pragma unroll
    for (int ch = 0; ch < 27; ++ch) acc[ch] = 0.f;

    const float* xb = x + (size_t)b * C1 * HWn;

    for (int cc = 0; cc < 4; ++cc) {       // 4 chunks of 8 channels
        __syncthreads();
        for (int idx = tid; idx < 8 * 324; idx += 256) {
            int cl  = idx / 324;
            int rem = idx - cl * 324;
            int r   = rem / 18;
            int col = rem - r * 18;
            int gh = h0 - 1 + r, gw = w0 - 1 + col;
            float v = 0.f;
            if (gh >= 0 && gh < Hc && gw >= 0 && gw < Wc)
                v = xb[(size_t)(c0 + cc * 8 + cl) * HWn + gh * Wc + gw];
            xs[cl][r][col] = v;
        }
        __syncthreads();
        #pragma unroll
        for (int cl = 0; cl < 8; ++cl) {
            float xr[9];
            #pragma unroll
            for (int kh = 0; kh < 3; ++kh)
                #pragma unroll
                for (int kw = 0; kw < 3; ++kw)
                    xr[kh * 3 + kw] = xs[cl][ph + kh][pw + kw];
            int c = c0 + cc * 8 + cl;
            const float* wp = w_off + (size_t)c * 9;
            #pragma unroll
            for (int ch = 0; ch < 27; ++ch) {
                const float* wc = wp + (size_t)ch * C1 * 9;  // uniform -> s_load
                #pragma unroll
                for (int p = 0; p < 9; ++p)
                    acc[ch] = fmaf(xr[p], wc[p], acc[ch]);
            }
        }
    }

    int hw = (h0 + ph) * Wc + (w0 + pw);
    float* ob = off + (size_t)b * OFFC * HWn + hw;
    #pragma unroll
    for (int ch = 0; ch < 27; ++ch)
        atomicAdd(ob + (size_t)ch * HWn, acc[ch]);
}

// ------------- kernel 2: deformable gather + split-bf16 MFMA GEMM v3 -------------
// BM=32 pixels, BN=256 oc, BK=32, grid 800 (XCD-chunked: 100 mtiles/XCD).
// A-path is REGISTER-DIRECT: each lane gathers exactly its MFMA A-fragment
// (pixel = mt*16 + li, channels kg*8..+8) -> no A-LDS, no A-barrier round-trip
// (round-6 lesson: step-serialized LDS staging was the limiter, not occupancy).
// B staged in LDS (40960B image) via global_load_lds; stage latency hides
// under the gather+combine phase between the two per-step barriers.
// LDS 46.7KB -> 3 blocks/CU (12 waves/CU). Split-bf16 3-term MFMA (fp32-grade).
__global__ __launch_bounds__(256) void k_dmfma(const float* __restrict__ x,
                                               const float* __restrict__ off,
                                               const unsigned short* __restrict__ wB,
                                               const float* __restrict__ bias,
                                               float* __restrict__ out)
{
    // LDS map (bytes):
    //   0     crd [288] int      (1152)
    //   1152  w4  [288] float4   (4608)
    //   5760  B   [2][256][40] u16 (40960)   total 46720
    //   epilogue: Tb [32][33] f32 (4224) aliases crd/w4 region
    __shared__ __align__(16) char smem[46720];
    int*    crd = (int*)(smem);
    float4* w4  = (float4*)(smem + 1152);
    unsigned short* Bb = (unsigned short*)(smem + 5760);
    float*  Tb  = (float*)(smem);

    int t  = threadIdx.x;
    // XCD-chunked swizzle: 800 = 8 XCDs x 100 contiguous mtiles.
    int mtile = ((blockIdx.x & 7) * 100) + (blockIdx.x >> 3);
    int m0  = mtile * 32;
    int b   = m0 / HWn;                // uniform (6400 % 32 == 0)
    int hw0 = m0 - b * HWn;
    const float* xb = x + (size_t)b * C1 * HWn;

    // ---- per-(pixel, p) bilinear metadata (32 px x 9 taps) ----
    for (int idx = t; idx < 288; idx += 256) {
        int pix = idx / 9;
        int p   = idx - pix * 9;
        int hw  = hw0 + pix;
        int h = hw / Wc, w = hw - h * Wc;
        int ii = p / 3, jj = p - ii * 3;
        const float* ob = off + (size_t)b * OFFC * HWn + hw;
        float dy = ob[(2 * p) * HWn];
        float dx = ob[(2 * p + 1) * HWn];
        float mv = ob[(18 + p) * HWn];
        float mask = 1.0f / (1.0f + expf(-mv));
        float ys = dy + (float)(h - 1 + ii);
        float xs = dx + (float)(w - 1 + jj);
        float y0f = floorf(ys), x0f = floorf(xs);
        float wy = ys - y0f, wx = xs - x0f;
        int y0 = (int)y0f, x0 = (int)x0f;
        int y1 = y0 + 1, x1 = x0 + 1;
        float vy0 = (y0 >= 0 && y0 < Hc) ? 1.f : 0.f;
        float vy1 = (y1 >= 0 && y1 < Hc) ? 1.f : 0.f;
        float vx0 = (x0 >= 0 && x0 < Wc) ? 1.f : 0.f;
        float vx1 = (x1 >= 0 && x1 < Wc) ? 1.f : 0.f;
        float4 wv;
        wv.x = mask * (1.f - wy) * (1.f - wx) * vy0 * vx0;
        wv.y = mask * (1.f - wy) * wx         * vy0 * vx1;
        wv.z = mask * wy         * (1.f - wx) * vy1 * vx0;
        wv.w = mask * wy         * wx         * vy1 * vx1;
        int cy0 = min(max(y0, 0), Hc - 1), cy1 = min(max(y1, 0), Hc - 1);
        int cx0 = min(max(x0, 0), Wc - 1), cx1 = min(max(x1, 0), Wc - 1);
        crd[idx] = cy0 | (cy1 << 8) | (cx0 << 16) | (cx1 << 24);
        w4[idx]  = wv;
    }

    f32x4 acc[8];
    #pragma unroll
    for (int n = 0; n < 8; ++n) acc[n] = (f32x4){0.f, 0.f, 0.f, 0.f};

    int wv_id = t >> 6, lane = t & 63;
    int li = lane & 15, kg = lane >> 4;
    int mt = wv_id & 1;                  // pixel 16-group
    int nh = wv_id >> 1;                 // oc 128-half
    int pixl = mt * 16 + li;             // this lane's pixel (local 0..31)

    __syncthreads();                     // metadata ready

    for (int s = 0; s < 72; ++s) {
        int p   = s >> 3;
        int c0s = (s & 7) << 5;
        __syncthreads();                 // B buffer free (prev MFMA done)
        // ---- stage B image for step s (40960 B) via global_load_lds ----
        {
            const char* bimg = (const char*)wB + (size_t)s * 40960;
            #pragma unroll
            for (int i = 0; i < 10; ++i) {
                int o = wv_id * 1024 + i * 4096;
                __builtin_amdgcn_global_load_lds(
                    (const __attribute__((address_space(1))) void*)(bimg + o + lane * 16),
                    (__attribute__((address_space(3))) void*)(smem + 5760 + o),
                    16, 0, 0);
            }
        }
        // ---- gather A-fragment directly into registers ----
        int cr    = crd[pixl * 9 + p];
        float4 wvv = w4[pixl * 9 + p];
        int cy0 = cr & 255, cy1 = (cr >> 8) & 255;
        int cx0 = (cr >> 16) & 255, cx1 = (cr >> 24) & 255;
        int o00 = cy0 * Wc + cx0, o01 = cy0 * Wc + cx1;
        int o10 = cy1 * Wc + cx0, o11 = cy1 * Wc + cx1;
        unsigned hu[4], lu[4];
        unsigned co = (unsigned)((c0s + kg * 8) * HWn);
        #pragma unroll
        for (int j = 0; j < 8; ++j) {
            float v = wvv.x * xb[co + o00] + wvv.y * xb[co + o01]
                    + wvv.z * xb[co + o10] + wvv.w * xb[co + o11];
            unsigned hb = f2bf(v);
            unsigned lb = f2bf(v - bf2f(hb));
            if (j & 1) { hu[j >> 1] |= hb << 16; lu[j >> 1] |= lb << 16; }
            else       { hu[j >> 1] = hb;        lu[j >> 1] = lb; }
            co += HWn;
        }
        bf16x8 ah = __builtin_bit_cast(bf16x8, make_uint4(hu[0], hu[1], hu[2], hu[3]));
        bf16x8 al = __builtin_bit_cast(bf16x8, make_uint4(lu[0], lu[1], lu[2], lu[3]));
        __syncthreads();                 // B stage complete (vmcnt drained)
        // ---- MFMA phase: 8 n-tiles x 3 split terms ----
        __builtin_amdgcn_s_setprio(1);
        #pragma unroll
        for (int nt = 0; nt < 8; ++nt) {
            int oc = nh * 128 + nt * 16 + li;
            bf16x8 bh = *(const bf16x8*)&Bb[oc * 40 + kg * 8];
            bf16x8 bl = *(const bf16x8*)&Bb[10240 + oc * 40 + kg * 8];
            acc[nt] = __builtin_amdgcn_mfma_f32_16x16x32_bf16(ah, bh, acc[nt], 0, 0, 0);
            acc[nt] = __builtin_amdgcn_mfma_f32_16x16x32_bf16(ah, bl, acc[nt], 0, 0, 0);
            acc[nt] = __builtin_amdgcn_mfma_f32_16x16x32_bf16(al, bh, acc[nt], 0, 0, 0);
        }
        __builtin_amdgcn_s_setprio(0);
    }

    // ---- epilogue: 8 phases through Tb[32][33] -> coalesced stores ----
    // D(lane, r): pixel = mt*16 + kg*4 + r, oc = nh*128 + nt*16 + li
    #pragma unroll
    for (int q = 0; q < 8; ++q) {
        __syncthreads();
        {
            f32x4 a = acc[q];
            int row = nh * 16 + li;          // 0..31
            int col = mt * 16 + kg * 4;      // 0..31
            #pragma unroll
            for (int r = 0; r < 4; ++r)
                Tb[row * 33 + col + r] = a[r];
        }
        __syncthreads();
        int px = t & 31;
        int rr = t >> 5;                     // 0..7
        #pragma unroll
        for (int it = 0; it < 4; ++it, rr += 8) {
            int oc = (rr >> 4) * 128 + q * 16 + (rr & 15);
            out[(size_t)(b * C2 + oc) * HWn + hw0 + px] = Tb[rr * 33 + px] + bias[oc];
        }
    }
}

// ---------------- kernel 3: BN stats (per-channel mean, invstd) ----------------
__global__ __launch_bounds__(256) void k_bnstats(const float* __restrict__ out,
                                                 float* __restrict__ stats)
{
    int oc = blockIdx.x;
    double s = 0.0, ss = 0.0;
    for (int i = threadIdx.x; i < NPIX; i += 256) {
        int bb = i / HWn;
        int hw = i - bb * HWn;
        float v = out[(size_t)(bb * C2 + oc) * HWn + hw];
        s  += (double)v;
        ss += (double)v * (double)v;
    }
    __shared__ double ls[256], lss[256];
    ls[threadIdx.x] = s; lss[threadIdx.x] = ss;
    __syncthreads();
    for (int st = 128; st > 0; st >>= 1) {
        if (threadIdx.x < st) {
            ls[threadIdx.x]  += ls[threadIdx.x + st];
            lss[threadIdx.x] += lss[threadIdx.x + st];
        }
        __syncthreads();
    }
    if (threadIdx.x == 0) {
        double mean = ls[0] / (double)NPIX;
        double var  = lss[0] / (double)NPIX - mean * mean;
        stats[oc]       = (float)mean;
        stats[256 + oc] = (float)(1.0 / sqrt(var + 1e-5));
    }
}

// ---------------- kernel 4: BN normalize + affine + SiLU (in-place) ----------------
__global__ __launch_bounds__(256) void k_bnsilu(float* __restrict__ out,
                                                const float* __restrict__ stats,
                                                const float* __restrict__ gamma,
                                                const float* __restrict__ beta)
{
    int n4 = (Bn * C2 * HWn) / 4;
    for (int i = blockIdx.x * blockDim.x + threadIdx.x; i < n4;
         i += gridDim.x * blockDim.x) {
        float4 v = ((float4*)out)[i];
        int e  = i * 4;
        int oc = (e / HWn) & 255;
        float mean = stats[oc];
        float gs   = gamma[oc] * stats[256 + oc];
        float bt   = beta[oc];
        float y;
        y = (v.x - mean) * gs + bt; v.x = y / (1.f + expf(-y));
        y = (v.y - mean) * gs + bt; v.y = y / (1.f + expf(-y));
        y = (v.z - mean) * gs + bt; v.z = y / (1.f + expf(-y));
        y = (v.w - mean) * gs + bt; v.w = y / (1.f + expf(-y));
        ((float4*)out)[i] = v;
    }
}

extern "C" void kernel_launch(void* const* d_in, const int* in_sizes, int n_in,
                              void* d_out, int out_size, void* d_ws, size_t ws_size,
                              hipStream_t stream)
{
    const float* x      = (const float*)d_in[0];
    const float* w_off  = (const float*)d_in[1];
    const float* b_off  = (const float*)d_in[2];
    const float* weight = (const float*)d_in[3];
    const float* bias   = (const float*)d_in[4];
    const float* gamma  = (const float*)d_in[5];
    const float* beta   = (const float*)d_in[6];
    float* out = (float*)d_out;

    float* ws    = (float*)d_ws;
    float* off   = ws;                                       // 691200 f
    unsigned short* wB = (unsigned short*)(ws + 691200);     // 1474560 u16
    float* stats = (float*)((char*)d_ws + 5713920);          // 512 f
    // total ws usage: ~5.7 MB

    k_wprep    <<<5760, 256, 0, stream>>>(weight, wB);
    k_offinit  <<<2700, 256, 0, stream>>>(b_off, off);
    k_offconv2 <<<800, 256, 0, stream>>>(x, w_off, off);
    k_dmfma    <<<800, 256, 0, stream>>>(x, off, wB, bias, out);
    k_bnstats  <<<256, 256, 0, stream>>>(out, stats);
    k_bnsilu   <<<2048, 256, 0, stream>>>(out, stats, gamma, beta);
}

// Round 8
// 567.785 us; speedup vs baseline: 1.2702x; 1.2702x over previous
//
#include <hip/hip_runtime.h>
#include <math.h>

constexpr int Hc = 80, Wc = 80, Bn = 4, C1 = 256, C2 = 256;
constexpr int HWn = Hc * Wc;          // 6400
constexpr int NPIX = Bn * HWn;        // 25600
constexpr int OFFC = 27;

typedef short bf16x8 __attribute__((ext_vector_type(8)));
typedef float f32x4  __attribute__((ext_vector_type(4)));

__device__ __forceinline__ unsigned f2bf(float f) {   // RNE to bf16 bits
    unsigned u = __float_as_uint(f);
    return (u + 0x7FFF + ((u >> 16) & 1)) >> 16;
}

// pack 2 floats -> hi-word (2 bf16) + lo-residual-word (2 bf16) via cvt_pk
__device__ __forceinline__ void pack2(float v0, float v1, unsigned& hw, unsigned& lw) {
    unsigned h;
    asm("v_cvt_pk_bf16_f32 %0, %1, %2" : "=v"(h) : "v"(v0), "v"(v1));
    float r0 = v0 - __uint_as_float(h << 16);
    float r1 = v1 - __uint_as_float(h & 0xffff0000u);
    unsigned l;
    asm("v_cvt_pk_bf16_f32 %0, %1, %2" : "=v"(l) : "v"(r0), "v"(r1));
    hw = h; lw = l;
}

// ---------------- kernel 0a: weight prep -> per-step B images (hi bf16 only) ----
// wB1[s][oc][40] bf16, s = p*8+cc (72 steps); kc<32 real, else pad 0
__global__ __launch_bounds__(256) void k_wprep(const float* __restrict__ weight,
                                               unsigned short* __restrict__ wB1)
{
    int e = blockIdx.x * 256 + threadIdx.x;   // 0 .. 737279
    int kc = e % 40;
    int oc = (e / 40) & 255;
    int s  = e / 10240;
    int p  = s >> 3, cc = s & 7;
    float w = 0.f;
    if (kc < 32) w = weight[((size_t)oc * C1 + cc * 32 + kc) * 9 + p];
    wB1[e] = (unsigned short)f2bf(w);
}

// ---------------- kernel 0b: offset-conv weight transpose -> wOT[c][244] -------
__global__ __launch_bounds__(256) void k_woprep(const float* __restrict__ w_off,
                                                float* __restrict__ wOT)
{
    int e = blockIdx.x * 256 + threadIdx.x;   // 0 .. 62463 (244 blocks)
    int c = e / 244, r = e - c * 244;
    float v = 0.f;
    if (r < 243) {
        int ch = r / 9, p = r - ch * 9;
        v = w_off[((size_t)ch * C1 + c) * 9 + p];
    }
    wOT[e] = v;
}

// ---------------- kernel 1a: init off buffer with b_off ----------------
__global__ __launch_bounds__(256) void k_offinit(const float* __restrict__ b_off,
                                                 float* __restrict__ off)
{
    int t = blockIdx.x * 256 + threadIdx.x;   // 0 .. 691199
    int ch = (t / HWn) % OFFC;
    off[t] = b_off[ch];
}

// ---------------- kernel 1b: offset conv v3 (LDS x-tile, unrolled reg weights) --
// round-7 diagnosis: 243 strided thread-uniform scalar loads per c were
// s_load-latency-bound (~215us). wOT[c][244] is contiguous -> 61 uniform
// float4 loads, fully unrolled with static acc indices.
__global__ __launch_bounds__(256) void k_offconv2(const float* __restrict__ x,
                                                  const float* __restrict__ wOT,
                                                  float* __restrict__ off)
{
    __shared__ float xs[8][18][18];

    int tid  = threadIdx.x;
    int bidx = blockIdx.x;                 // 0..799
    int wt = bidx % 5;
    int ht = (bidx / 5) % 5;
    int b  = (bidx / 25) % 4;
    int cg = bidx / 100;                   // 0..7
    int h0 = ht * 16, w0 = wt * 16;
    int c0 = cg * 32;
    int ph = tid >> 4, pw = tid & 15;

    float acc[27];
    #pragma unroll
    for (int ch = 0; ch < 27; ++ch) acc[ch] = 0.f;

    const float* xb = x + (size_t)b * C1 * HWn;

    for (int cc = 0; cc < 4; ++cc) {       // 4 chunks of 8 channels
        __syncthreads();
        for (int idx = tid; idx < 8 * 324; idx += 256) {
            int cl  = idx / 324;
            int rem = idx - cl * 324;
            int r   = rem / 18;
            int col = rem - r * 18;
            int gh = h0 - 1 + r, gw = w0 - 1 + col;
            float v = 0.f;
            if (gh >= 0 && gh < Hc && gw >= 0 && gw < Wc)
                v = xb[(size_t)(c0 + cc * 8 + cl) * HWn + gh * Wc + gw];
            xs[cl][r][col] = v;
        }
        __syncthreads();
        #pragma unroll
        for (int cl = 0; cl < 8; ++cl) {
            float xr[9];
            #pragma unroll
            for (int kh = 0; kh < 3; ++kh)
                #pragma unroll
                for (int kw = 0; kw < 3; ++kw)
                    xr[kh * 3 + kw] = xs[cl][ph + kh][pw + kw];
            int c = c0 + cc * 8 + cl;
            const float4* wv4 = (const float4*)&wOT[c * 244];
            #pragma unroll
            for (int j = 0; j < 61; ++j) {
                float4 wj = wv4[j];
                #pragma unroll
                for (int u = 0; u < 4; ++u) {
                    constexpr int NW = 243;
                    int idx = 4 * j + u;
                    if (idx < NW)
                        acc[idx / 9] = fmaf(xr[idx % 9], (&wj.x)[u], acc[idx / 9]);
                }
            }
        }
    }

    int hw = (h0 + ph) * Wc + (w0 + pw);
    float* ob = off + (size_t)b * OFFC * HWn + hw;
    #pragma unroll
    for (int ch = 0; ch < 27; ++ch)
        atomicAdd(ob + (size_t)ch * HWn, acc[ch]);
}

// ------------- kernel 2: deformable gather + MFMA GEMM v4 (pipelined) -------------
// BM=64 (4 m-tiles), BN=256 (16 n-tiles), BK=32, grid 400, XCD-chunked (50/XCD).
// 4 waves: wave(ms,ns) = 2 m-tiles x 8 n-tiles. A = reg-direct gather, hi/lo
// split; B = single bf16 (weights: err ~1e-3 post-BN), double-buffered LDS,
// staged via global_load_lds one step ahead (single barrier per step — the
// gll(s+1) latency hides under MFMA(s)+gather(s+1); vmcnt FIFO drains gll(s)
// at combine(s) since it is older than the gathers).
// LDS 52.5KB -> 3 blocks/CU (12 waves/CU).
__global__ __launch_bounds__(256, 3) void k_dmfma(const float* __restrict__ x,
                                                  const float* __restrict__ off,
                                                  const unsigned short* __restrict__ wB1,
                                                  const float* __restrict__ bias,
                                                  float* __restrict__ out)
{
    // LDS map (bytes):
    //   0      crd [576] int     (2304)
    //   2304   w4  [576] float4  (9216)
    //   11520  B dbuf [2][256][40] u16 (40960)   total 52480
    //   epilogue: Tb [32][66] f32 (8448) aliases crd/w4 region
    __shared__ __align__(16) char smem[52480];
    int*    crd = (int*)(smem);
    float4* w4  = (float4*)(smem + 2304);
    float*  Tb  = (float*)(smem);

    int t    = threadIdx.x;
    int wv   = t >> 6, lane = t & 63;
    int li   = lane & 15, kg = lane >> 4;
    int ms   = wv & 1;                 // m-slot (2 m-tiles each)
    int ns   = wv >> 1;                // n-slot (128 oc each)

    // XCD-chunked swizzle: 400 = 8 XCDs x 50 contiguous mtiles.
    int mtile = ((blockIdx.x & 7) * 50) + (blockIdx.x >> 3);
    int m0  = mtile * 64;
    int b   = m0 / HWn;                // uniform (6400 % 64 == 0)
    int hw0 = m0 - b * HWn;
    const float* xb = x + (size_t)b * C1 * HWn;

    // ---- prefetch B image for step 0 (overlaps metadata compute) ----
    {
        const char* src = (const char*)wB1 + wv * 5120 + lane * 16;
        #pragma unroll
        for (int i = 0; i < 5; ++i)
            __builtin_amdgcn_global_load_lds(
                (const __attribute__((address_space(1))) void*)(src + i * 1024),
                (__attribute__((address_space(3))) void*)(smem + 11520 + wv * 5120 + i * 1024),
                16, 0, 0);
    }

    // ---- per-(pixel, tap) bilinear metadata (64 px x 9 taps) ----
    for (int idx = t; idx < 576; idx += 256) {
        int pix = idx / 9;
        int p   = idx - pix * 9;
        int hw  = hw0 + pix;
        int h = hw / Wc, w = hw - h * Wc;
        int ii = p / 3, jj = p - ii * 3;
        const float* ob = off + (size_t)b * OFFC * HWn + hw;
        float dy = ob[(2 * p) * HWn];
        float dx = ob[(2 * p + 1) * HWn];
        float mv = ob[(18 + p) * HWn];
        float mask = 1.0f / (1.0f + expf(-mv));
        float ys = dy + (float)(h - 1 + ii);
        float xsv = dx + (float)(w - 1 + jj);
        float y0f = floorf(ys), x0f = floorf(xsv);
        float wy = ys - y0f, wx = xsv - x0f;
        int y0 = (int)y0f, x0 = (int)x0f;
        int y1 = y0 + 1, x1 = x0 + 1;
        float vy0 = (y0 >= 0 && y0 < Hc) ? 1.f : 0.f;
        float vy1 = (y1 >= 0 && y1 < Hc) ? 1.f : 0.f;
        float vx0 = (x0 >= 0 && x0 < Wc) ? 1.f : 0.f;
        float vx1 = (x1 >= 0 && x1 < Wc) ? 1.f : 0.f;
        float4 wvv;
        wvv.x = mask * (1.f - wy) * (1.f - wx) * vy0 * vx0;
        wvv.y = mask * (1.f - wy) * wx         * vy0 * vx1;
        wvv.z = mask * wy         * (1.f - wx) * vy1 * vx0;
        wvv.w = mask * wy         * wx         * vy1 * vx1;
        int cy0 = min(max(y0, 0), Hc - 1), cy1 = min(max(y1, 0), Hc - 1);
        int cx0 = min(max(x0, 0), Wc - 1), cx1 = min(max(x1, 0), Wc - 1);
        crd[idx] = cy0 | (cy1 << 8) | (cx0 << 16) | (cx1 << 24);
        w4[idx]  = wvv;
    }
    __syncthreads();          // metadata ready; gll(0) also drained here

    f32x4 acc[2][8];
    #pragma unroll
    for (int m = 0; m < 2; ++m)
        #pragma unroll
        for (int n = 0; n < 8; ++n)
            acc[m][n] = (f32x4){0.f, 0.f, 0.f, 0.f};

    for (int s = 0; s < 72; ++s) {
        int cur = s & 1;
        int p   = s >> 3;
        int c0s = (s & 7) << 5;
        // ---- gather A-fragments for 2 m-tiles directly into registers ----
        bf16x8 ah[2], al[2];
        #pragma unroll
        for (int m = 0; m < 2; ++m) {
            int pix = ms * 32 + m * 16 + li;
            int cr  = crd[pix * 9 + p];
            float4 wvv = w4[pix * 9 + p];
            int cy0 = cr & 255, cy1 = (cr >> 8) & 255;
            int cx0 = (cr >> 16) & 255, cx1 = (cr >> 24) & 255;
            int o00 = cy0 * Wc + cx0, o01 = cy0 * Wc + cx1;
            int o10 = cy1 * Wc + cx0, o11 = cy1 * Wc + cx1;
            float v[8];
            unsigned co = (unsigned)((c0s + kg * 8) * HWn);
            #pragma unroll
            for (int j = 0; j < 8; ++j) {
                v[j] = wvv.x * xb[co + o00] + wvv.y * xb[co + o01]
                     + wvv.z * xb[co + o10] + wvv.w * xb[co + o11];
                co += HWn;
            }
            unsigned hu[4], lu[4];
            #pragma unroll
            for (int j = 0; j < 4; ++j) pack2(v[2 * j], v[2 * j + 1], hu[j], lu[j]);
            ah[m] = __builtin_bit_cast(bf16x8, make_uint4(hu[0], hu[1], hu[2], hu[3]));
            al[m] = __builtin_bit_cast(bf16x8, make_uint4(lu[0], lu[1], lu[2], lu[3]));
        }
        __syncthreads();   // buf[cur] complete (own gll(s) drained by combine,
                           // all waves past MFMA(s-1) reads of buf[cur^1])
        // ---- prefetch B image for step s+1 into the other buffer ----
        if (s < 71) {
            const char* src = (const char*)wB1 + (size_t)(s + 1) * 20480 + wv * 5120 + lane * 16;
            char* dst = smem + 11520 + (cur ^ 1) * 20480 + wv * 5120;
            #pragma unroll
            for (int i = 0; i < 5; ++i)
                __builtin_amdgcn_global_load_lds(
                    (const __attribute__((address_space(1))) void*)(src + i * 1024),
                    (__attribute__((address_space(3))) void*)(dst + i * 1024),
                    16, 0, 0);
        }
        // ---- MFMA phase: 8 n-tiles x 2 m-tiles x 2 A-splits ----
        const unsigned short* Bcur = (const unsigned short*)(smem + 11520 + cur * 20480);
        __builtin_amdgcn_s_setprio(1);
        #pragma unroll
        for (int nt = 0; nt < 8; ++nt) {
            int oc = ns * 128 + nt * 16 + li;
            bf16x8 bv = *(const bf16x8*)&Bcur[oc * 40 + kg * 8];
            acc[0][nt] = __builtin_amdgcn_mfma_f32_16x16x32_bf16(ah[0], bv, acc[0][nt], 0, 0, 0);
            acc[1][nt] = __builtin_amdgcn_mfma_f32_16x16x32_bf16(ah[1], bv, acc[1][nt], 0, 0, 0);
            acc[0][nt] = __builtin_amdgcn_mfma_f32_16x16x32_bf16(al[0], bv, acc[0][nt], 0, 0, 0);
            acc[1][nt] = __builtin_amdgcn_mfma_f32_16x16x32_bf16(al[1], bv, acc[1][nt], 0, 0, 0);
        }
        __builtin_amdgcn_s_setprio(0);
    }

    // ---- epilogue: 8 phases of 32 oc through Tb[32][66] ----
    // D frag: pixel = ms*32 + m*16 + kg*4 + r ; oc = ns*128 + nt*16 + li
    #pragma unroll
    for (int q = 0; q < 8; ++q) {
        __syncthreads();
        if (ns == (q >> 2)) {
            #pragma unroll
            for (int j = 0; j < 2; ++j) {
                int nt = (q & 3) * 2 + j;
                #pragma unroll
                for (int m = 0; m < 2; ++m) {
                    f32x4 a = acc[m][nt];
                    int row = j * 16 + li;                 // oc within phase
                    int col = ms * 32 + m * 16 + kg * 4;   // pixel
                    #pragma unroll
                    for (int r = 0; r < 4; ++r)
                        Tb[row * 66 + col + r] = a[r];
                }
            }
        }
        __syncthreads();
        int px = t & 63;
        int rr = t >> 6;                    // 0..3
        #pragma unroll
        for (int it = 0; it < 8; ++it) {
            int r  = rr * 8 + it;           // 0..31
            int oc = q * 32 + r;
            out[(size_t)(b * C2 + oc) * HWn + hw0 + px] = Tb[r * 66 + px] + bias[oc];
        }
    }
}

// ---------------- kernel 3: BN stats (per-channel mean, invstd) ----------------
__global__ __launch_bounds__(256) void k_bnstats(const float* __restrict__ out,
                                                 float* __restrict__ stats)
{
    int oc = blockIdx.x;
    double s = 0.0, ss = 0.0;
    for (int i = threadIdx.x; i < NPIX; i += 256) {
        int bb = i / HWn;
        int hw = i - bb * HWn;
        float v = out[(size_t)(bb * C2 + oc) * HWn + hw];
        s  += (double)v;
        ss += (double)v * (double)v;
    }
    __shared__ double ls[256], lss[256];
    ls[threadIdx.x] = s; lss[threadIdx.x] = ss;
    __syncthreads();
    for (int st = 128; st > 0; st >>= 1) {
        if (threadIdx.x < st) {
            ls[threadIdx.x]  += ls[threadIdx.x + st];
            lss[threadIdx.x] += lss[threadIdx.x + st];
        }
        __syncthreads();
    }
    if (threadIdx.x == 0) {
        double mean = ls[0] / (double)NPIX;
        double var  = lss[0] / (double)NPIX - mean * mean;
        stats[oc]       = (float)mean;
        stats[256 + oc] = (float)(1.0 / sqrt(var + 1e-5));
    }
}

// ---------------- kernel 4: BN normalize + affine + SiLU (in-place) ----------------
__global__ __launch_bounds__(256) void k_bnsilu(float* __restrict__ out,
                                                const float* __restrict__ stats,
                                                const float* __restrict__ gamma,
                                                const float* __restrict__ beta)
{
    int n4 = (Bn * C2 * HWn) / 4;
    for (int i = blockIdx.x * blockDim.x + threadIdx.x; i < n4;
         i += gridDim.x * blockDim.x) {
        float4 v = ((float4*)out)[i];
        int e  = i * 4;
        int oc = (e / HWn) & 255;
        float mean = stats[oc];
        float gs   = gamma[oc] * stats[256 + oc];
        float bt   = beta[oc];
        float y;
        y = (v.x - mean) * gs + bt; v.x = y / (1.f + expf(-y));
        y = (v.y - mean) * gs + bt; v.y = y / (1.f + expf(-y));
        y = (v.z - mean) * gs + bt; v.z = y / (1.f + expf(-y));
        y = (v.w - mean) * gs + bt; v.w = y / (1.f + expf(-y));
        ((float4*)out)[i] = v;
    }
}

extern "C" void kernel_launch(void* const* d_in, const int* in_sizes, int n_in,
                              void* d_out, int out_size, void* d_ws, size_t ws_size,
                              hipStream_t stream)
{
    const float* x      = (const float*)d_in[0];
    const float* w_off  = (const float*)d_in[1];
    const float* b_off  = (const float*)d_in[2];
    const float* weight = (const float*)d_in[3];
    const float* bias   = (const float*)d_in[4];
    const float* gamma  = (const float*)d_in[5];
    const float* beta   = (const float*)d_in[6];
    float* out = (float*)d_out;

    float* ws = (float*)d_ws;
    float*          off   = ws;                               // 691200 f
    unsigned short* wB1   = (unsigned short*)(ws + 691200);   // 737280 u16
    float*          wOT   = ws + 691200 + 368640;             // 62464 f
    float*          stats = wOT + 62464;                      // 512 f
    // total ws usage: ~4.5 MB

    k_wprep    <<<2880, 256, 0, stream>>>(weight, wB1);
    k_woprep   <<<244, 256, 0, stream>>>(w_off, wOT);
    k_offinit  <<<2700, 256, 0, stream>>>(b_off, off);
    k_offconv2 <<<800, 256, 0, stream>>>(x, wOT, off);
    k_dmfma    <<<400, 256, 0, stream>>>(x, off, wB1, bias, out);
    k_bnstats  <<<256, 256, 0, stream>>>(out, stats);
    k_bnsilu   <<<2048, 256, 0, stream>>>(out, stats, gamma, beta);
}

// Round 9
// 562.873 us; speedup vs baseline: 1.2813x; 1.0087x over previous
//
#include <hip/hip_runtime.h>
#include <math.h>

constexpr int Hc = 80, Wc = 80, Bn = 4, C1 = 256, C2 = 256;
constexpr int HWn = Hc * Wc;          // 6400
constexpr int NPIX = Bn * HWn;        // 25600
constexpr int OFFC = 27;

typedef short bf16x8 __attribute__((ext_vector_type(8)));
typedef float f32x4  __attribute__((ext_vector_type(4)));

__device__ __forceinline__ unsigned f2bf(float f) {   // RNE to bf16 bits
    unsigned u = __float_as_uint(f);
    return (u + 0x7FFF + ((u >> 16) & 1)) >> 16;
}

// pack 2 floats -> hi-word (2 bf16) + lo-residual-word (2 bf16) via cvt_pk
__device__ __forceinline__ void pack2(float v0, float v1, unsigned& hw, unsigned& lw) {
    unsigned h;
    asm("v_cvt_pk_bf16_f32 %0, %1, %2" : "=v"(h) : "v"(v0), "v"(v1));
    float r0 = v0 - __uint_as_float(h << 16);
    float r1 = v1 - __uint_as_float(h & 0xffff0000u);
    unsigned l;
    asm("v_cvt_pk_bf16_f32 %0, %1, %2" : "=v"(l) : "v"(r0), "v"(r1));
    hw = h; lw = l;
}

// ---------------- kernel 0a: weight prep -> per-step B images (hi bf16 only) ----
// wB1[s][oc][40] bf16, s = p*8+cc (72 steps); kc<32 real, else pad 0
__global__ __launch_bounds__(256) void k_wprep(const float* __restrict__ weight,
                                               unsigned short* __restrict__ wB1)
{
    int e = blockIdx.x * 256 + threadIdx.x;   // 0 .. 737279
    int kc = e % 40;
    int oc = (e / 40) & 255;
    int s  = e / 10240;
    int p  = s >> 3, cc = s & 7;
    float w = 0.f;
    if (kc < 32) w = weight[((size_t)oc * C1 + cc * 32 + kc) * 9 + p];
    wB1[e] = (unsigned short)f2bf(w);
}

// ---------------- kernel 0b: offset-conv weight transpose -> wOT[c][244] -------
__global__ __launch_bounds__(256) void k_woprep(const float* __restrict__ w_off,
                                                float* __restrict__ wOT)
{
    int e = blockIdx.x * 256 + threadIdx.x;   // 0 .. 62463 (244 blocks)
    int c = e / 244, r = e - c * 244;
    float v = 0.f;
    if (r < 243) {
        int ch = r / 9, p = r - ch * 9;
        v = w_off[((size_t)ch * C1 + c) * 9 + p];
    }
    wOT[e] = v;
}

// ---------------- kernel 1a: init off buffer with b_off ----------------
__global__ __launch_bounds__(256) void k_offinit(const float* __restrict__ b_off,
                                                 float* __restrict__ off)
{
    int t = blockIdx.x * 256 + threadIdx.x;   // 0 .. 691199
    int ch = (t / HWn) % OFFC;
    off[t] = b_off[ch];
}

// ---------------- kernel 1b: offset conv v3 (LDS x-tile, unrolled reg weights) --
__global__ __launch_bounds__(256) void k_offconv2(const float* __restrict__ x,
                                                  const float* __restrict__ wOT,
                                                  float* __restrict__ off)
{
    __shared__ float xs[8][18][18];

    int tid  = threadIdx.x;
    int bidx = blockIdx.x;                 // 0..799
    int wt = bidx % 5;
    int ht = (bidx / 5) % 5;
    int b  = (bidx / 25) % 4;
    int cg = bidx / 100;                   // 0..7
    int h0 = ht * 16, w0 = wt * 16;
    int c0 = cg * 32;
    int ph = tid >> 4, pw = tid & 15;

    float acc[27];
    #pragma unroll
    for (int ch = 0; ch < 27; ++ch) acc[ch] = 0.f;

    const float* xb = x + (size_t)b * C1 * HWn;

    for (int cc = 0; cc < 4; ++cc) {       // 4 chunks of 8 channels
        __syncthreads();
        for (int idx = tid; idx < 8 * 324; idx += 256) {
            int cl  = idx / 324;
            int rem = idx - cl * 324;
            int r   = rem / 18;
            int col = rem - r * 18;
            int gh = h0 - 1 + r, gw = w0 - 1 + col;
            float v = 0.f;
            if (gh >= 0 && gh < Hc && gw >= 0 && gw < Wc)
                v = xb[(size_t)(c0 + cc * 8 + cl) * HWn + gh * Wc + gw];
            xs[cl][r][col] = v;
        }
        __syncthreads();
        #pragma unroll
        for (int cl = 0; cl < 8; ++cl) {
            float xr[9];
            #pragma unroll
            for (int kh = 0; kh < 3; ++kh)
                #pragma unroll
                for (int kw = 0; kw < 3; ++kw)
                    xr[kh * 3 + kw] = xs[cl][ph + kh][pw + kw];
            int c = c0 + cc * 8 + cl;
            const float4* wv4 = (const float4*)&wOT[c * 244];
            #pragma unroll
            for (int j = 0; j < 61; ++j) {
                float4 wj = wv4[j];
                #pragma unroll
                for (int u = 0; u < 4; ++u) {
                    constexpr int NW = 243;
                    int idx = 4 * j + u;
                    if (idx < NW)
                        acc[idx / 9] = fmaf(xr[idx % 9], (&wj.x)[u], acc[idx / 9]);
                }
            }
        }
    }

    int hw = (h0 + ph) * Wc + (w0 + pw);
    float* ob = off + (size_t)b * OFFC * HWn + hw;
    #pragma unroll
    for (int ch = 0; ch < 27; ++ch)
        atomicAdd(ob + (size_t)ch * HWn, acc[ch]);
}

// ------------- kernel 2: deformable gather + MFMA GEMM v5 -------------
// BM=32 (2 m-tiles), BN=256, BK=32, grid 800, XCD-chunked (100 mtiles/XCD).
// round-8 lesson: grid 400 capped residency at ~1.3 blocks/CU -> gather
// latency-bound (70cyc/load). Now: 800 blocks, LDS 46.7KB -> 3 blocks/CU
// (12 waves/CU); per-lane gather halved to 32 loads/step, issued as one
// burst (load-arrays first, combine after) for MLP.
// 4 waves: wave(mi,nh) = 1 m-tile x 8 n-tiles. A reg-direct hi/lo split;
// B single bf16 dbuf LDS via global_load_lds one step ahead; 1 barrier/step.
__global__ __launch_bounds__(256, 3) void k_dmfma(const float* __restrict__ x,
                                                  const float* __restrict__ off,
                                                  const unsigned short* __restrict__ wB1,
                                                  const float* __restrict__ bias,
                                                  float* __restrict__ out)
{
    // LDS map (bytes):
    //   0      crd [288] int     (1152)
    //   1152   w4  [288] float4  (4608)
    //   5760   B dbuf [2][256][40] u16 (40960)   total 46720
    //   epilogue: Tb [32][33] f32 (4224) aliases crd/w4 region
    __shared__ __align__(16) char smem[46720];
    int*    crd = (int*)(smem);
    float4* w4  = (float4*)(smem + 1152);
    float*  Tb  = (float*)(smem);

    int t    = threadIdx.x;
    int wv   = t >> 6, lane = t & 63;
    int li   = lane & 15, kg = lane >> 4;
    int mi   = wv & 1;                 // m-tile (16 px)
    int nh   = wv >> 1;                // oc 128-half
    int pixl = mi * 16 + li;           // this lane's pixel (local 0..31)

    // XCD-chunked swizzle: 800 = 8 XCDs x 100 contiguous mtiles.
    int mtile = ((blockIdx.x & 7) * 100) + (blockIdx.x >> 3);
    int m0  = mtile * 32;
    int b   = m0 / HWn;                // uniform (6400 % 32 == 0)
    int hw0 = m0 - b * HWn;
    const float* xb = x + (size_t)b * C1 * HWn;

    // ---- prefetch B image for step 0 (overlaps metadata compute) ----
    {
        const char* src = (const char*)wB1 + wv * 5120 + lane * 16;
        #pragma unroll
        for (int i = 0; i < 5; ++i)
            __builtin_amdgcn_global_load_lds(
                (const __attribute__((address_space(1))) void*)(src + i * 1024),
                (__attribute__((address_space(3))) void*)(smem + 5760 + wv * 5120 + i * 1024),
                16, 0, 0);
    }

    // ---- per-(pixel, tap) bilinear metadata (32 px x 9 taps) ----
    for (int idx = t; idx < 288; idx += 256) {
        int pix = idx / 9;
        int p   = idx - pix * 9;
        int hw  = hw0 + pix;
        int h = hw / Wc, w = hw - h * Wc;
        int ii = p / 3, jj = p - ii * 3;
        const float* ob = off + (size_t)b * OFFC * HWn + hw;
        float dy = ob[(2 * p) * HWn];
        float dx = ob[(2 * p + 1) * HWn];
        float mv = ob[(18 + p) * HWn];
        float mask = 1.0f / (1.0f + expf(-mv));
        float ys = dy + (float)(h - 1 + ii);
        float xsv = dx + (float)(w - 1 + jj);
        float y0f = floorf(ys), x0f = floorf(xsv);
        float wy = ys - y0f, wx = xsv - x0f;
        int y0 = (int)y0f, x0 = (int)x0f;
        int y1 = y0 + 1, x1 = x0 + 1;
        float vy0 = (y0 >= 0 && y0 < Hc) ? 1.f : 0.f;
        float vy1 = (y1 >= 0 && y1 < Hc) ? 1.f : 0.f;
        float vx0 = (x0 >= 0 && x0 < Wc) ? 1.f : 0.f;
        float vx1 = (x1 >= 0 && x1 < Wc) ? 1.f : 0.f;
        float4 wvv;
        wvv.x = mask * (1.f - wy) * (1.f - wx) * vy0 * vx0;
        wvv.y = mask * (1.f - wy) * wx         * vy0 * vx1;
        wvv.z = mask * wy         * (1.f - wx) * vy1 * vx0;
        wvv.w = mask * wy         * wx         * vy1 * vx1;
        int cy0 = min(max(y0, 0), Hc - 1), cy1 = min(max(y1, 0), Hc - 1);
        int cx0 = min(max(x0, 0), Wc - 1), cx1 = min(max(x1, 0), Wc - 1);
        crd[idx] = cy0 | (cy1 << 8) | (cx0 << 16) | (cx1 << 24);
        w4[idx]  = wvv;
    }
    __syncthreads();          // metadata ready; gll(0) also drained here

    f32x4 acc[8];
    #pragma unroll
    for (int n = 0; n < 8; ++n) acc[n] = (f32x4){0.f, 0.f, 0.f, 0.f};

    for (int s = 0; s < 72; ++s) {
        int cur = s & 1;
        int p   = s >> 3;
        int c0s = (s & 7) << 5;
        // ---- gather: issue all 32 loads first (MLP), combine after ----
        int cr  = crd[pixl * 9 + p];
        float4 wvv = w4[pixl * 9 + p];
        int cy0 = cr & 255, cy1 = (cr >> 8) & 255;
        int cx0 = (cr >> 16) & 255, cx1 = (cr >> 24) & 255;
        int o00 = cy0 * Wc + cx0, o01 = cy0 * Wc + cx1;
        int o10 = cy1 * Wc + cx0, o11 = cy1 * Wc + cx1;
        float g00[8], g01[8], g10[8], g11[8];
        {
            unsigned co = (unsigned)((c0s + kg * 8) * HWn);
            #pragma unroll
            for (int j = 0; j < 8; ++j) {
                g00[j] = xb[co + o00];
                g01[j] = xb[co + o01];
                g10[j] = xb[co + o10];
                g11[j] = xb[co + o11];
                co += HWn;
            }
        }
        float v[8];
        #pragma unroll
        for (int j = 0; j < 8; ++j)
            v[j] = fmaf(wvv.x, g00[j], fmaf(wvv.y, g01[j],
                   fmaf(wvv.z, g10[j], wvv.w * g11[j])));
        unsigned hu[4], lu[4];
        #pragma unroll
        for (int j = 0; j < 4; ++j) pack2(v[2 * j], v[2 * j + 1], hu[j], lu[j]);
        bf16x8 ah = __builtin_bit_cast(bf16x8, make_uint4(hu[0], hu[1], hu[2], hu[3]));
        bf16x8 al = __builtin_bit_cast(bf16x8, make_uint4(lu[0], lu[1], lu[2], lu[3]));
        __syncthreads();   // all waves past MFMA(s-1); gll(s)+gathers drained
        // ---- prefetch B image for step s+1 into the other buffer ----
        if (s < 71) {
            const char* src = (const char*)wB1 + (size_t)(s + 1) * 20480 + wv * 5120 + lane * 16;
            char* dst = smem + 5760 + (cur ^ 1) * 20480 + wv * 5120;
            #pragma unroll
            for (int i = 0; i < 5; ++i)
                __builtin_amdgcn_global_load_lds(
                    (const __attribute__((address_space(1))) void*)(src + i * 1024),
                    (__attribute__((address_space(3))) void*)(dst + i * 1024),
                    16, 0, 0);
        }
        // ---- MFMA phase: 8 n-tiles x 2 A-splits ----
        const unsigned short* Bcur = (const unsigned short*)(smem + 5760 + cur * 20480);
        __builtin_amdgcn_s_setprio(1);
        #pragma unroll
        for (int nt = 0; nt < 8; ++nt) {
            int oc = nh * 128 + nt * 16 + li;
            bf16x8 bv = *(const bf16x8*)&Bcur[oc * 40 + kg * 8];
            acc[nt] = __builtin_amdgcn_mfma_f32_16x16x32_bf16(ah, bv, acc[nt], 0, 0, 0);
            acc[nt] = __builtin_amdgcn_mfma_f32_16x16x32_bf16(al, bv, acc[nt], 0, 0, 0);
        }
        __builtin_amdgcn_s_setprio(0);
    }

    // ---- epilogue: 8 phases of 32 oc through Tb[32][33] ----
    // D frag: pixel = mi*16 + kg*4 + r ; oc = nh*128 + nt*16 + li
    #pragma unroll
    for (int q = 0; q < 8; ++q) {
        __syncthreads();
        if (nh == (q >> 2)) {
            #pragma unroll
            for (int j = 0; j < 2; ++j) {
                int nt = (q & 3) * 2 + j;
                f32x4 a = acc[nt];
                int row = j * 16 + li;              // oc row 0..31
                int col = mi * 16 + kg * 4;         // pixel col
                #pragma unroll
                for (int r = 0; r < 4; ++r)
                    Tb[row * 33 + col + r] = a[r];
            }
        }
        __syncthreads();
        int px = t & 31;
        int rw = t >> 5;                    // 0..7
        #pragma unroll
        for (int it = 0; it < 4; ++it) {
            int r  = it * 8 + rw;           // 0..31
            int oc = q * 32 + r;
            out[(size_t)(b * C2 + oc) * HWn + hw0 + px] = Tb[r * 33 + px] + bias[oc];
        }
    }
}

// ---------------- kernel 3: BN stats (per-channel mean, invstd) ----------------
__global__ __launch_bounds__(256) void k_bnstats(const float* __restrict__ out,
                                                 float* __restrict__ stats)
{
    int oc = blockIdx.x;
    double s = 0.0, ss = 0.0;
    for (int i = threadIdx.x; i < NPIX; i += 256) {
        int bb = i / HWn;
        int hw = i - bb * HWn;
        float v = out[(size_t)(bb * C2 + oc) * HWn + hw];
        s  += (double)v;
        ss += (double)v * (double)v;
    }
    __shared__ double ls[256], lss[256];
    ls[threadIdx.x] = s; lss[threadIdx.x] = ss;
    __syncthreads();
    for (int st = 128; st > 0; st >>= 1) {
        if (threadIdx.x < st) {
            ls[threadIdx.x]  += ls[threadIdx.x + st];
            lss[threadIdx.x] += lss[threadIdx.x + st];
        }
        __syncthreads();
    }
    if (threadIdx.x == 0) {
        double mean = ls[0] / (double)NPIX;
        double var  = lss[0] / (double)NPIX - mean * mean;
        stats[oc]       = (float)mean;
        stats[256 + oc] = (float)(1.0 / sqrt(var + 1e-5));
    }
}

// ---------------- kernel 4: BN normalize + affine + SiLU (in-place) ----------------
__global__ __launch_bounds__(256) void k_bnsilu(float* __restrict__ out,
                                                const float* __restrict__ stats,
                                                const float* __restrict__ gamma,
                                                const float* __restrict__ beta)
{
    int n4 = (Bn * C2 * HWn) / 4;
    for (int i = blockIdx.x * blockDim.x + threadIdx.x; i < n4;
         i += gridDim.x * blockDim.x) {
        float4 v = ((float4*)out)[i];
        int e  = i * 4;
        int oc = (e / HWn) & 255;
        float mean = stats[oc];
        float gs   = gamma[oc] * stats[256 + oc];
        float bt   = beta[oc];
        float y;
        y = (v.x - mean) * gs + bt; v.x = y / (1.f + expf(-y));
        y = (v.y - mean) * gs + bt; v.y = y / (1.f + expf(-y));
        y = (v.z - mean) * gs + bt; v.z = y / (1.f + expf(-y));
        y = (v.w - mean) * gs + bt; v.w = y / (1.f + expf(-y));
        ((float4*)out)[i] = v;
    }
}

extern "C" void kernel_launch(void* const* d_in, const int* in_sizes, int n_in,
                              void* d_out, int out_size, void* d_ws, size_t ws_size,
                              hipStream_t stream)
{
    const float* x      = (const float*)d_in[0];
    const float* w_off  = (const float*)d_in[1];
    const float* b_off  = (const float*)d_in[2];
    const float* weight = (const float*)d_in[3];
    const float* bias   = (const float*)d_in[4];
    const float* gamma  = (const float*)d_in[5];
    const float* beta   = (const float*)d_in[6];
    float* out = (float*)d_out;

    float* ws = (float*)d_ws;
    float*          off   = ws;                               // 691200 f
    unsigned short* wB1   = (unsigned short*)(ws + 691200);   // 737280 u16
    float*          wOT   = ws + 691200 + 368640;             // 62464 f
    float*          stats = wOT + 62464;                      // 512 f
    // total ws usage: ~4.5 MB

    k_wprep    <<<2880, 256, 0, stream>>>(weight, wB1);
    k_woprep   <<<244, 256, 0, stream>>>(w_off, wOT);
    k_offinit  <<<2700, 256, 0, stream>>>(b_off, off);
    k_offconv2 <<<800, 256, 0, stream>>>(x, wOT, off);
    k_dmfma    <<<800, 256, 0, stream>>>(x, off, wB1, bias, out);
    k_bnstats  <<<256, 256, 0, stream>>>(out, stats);
    k_bnsilu   <<<2048, 256, 0, stream>>>(out, stats, gamma, beta);
}